// Round 10
// baseline (309.439 us; speedup 1.0000x reference)
//
#include <hip/hip_runtime.h>

#define H 4096
#define W 4096
#define TR 16                  // rows per block
#define BX 256                 // threads per block (4 waves)
#define SW 512                 // strip width = BX * 2 cols
#define NSTRIP (W / SW)        // 8
#define GY (H / TR)            // 256
#define NB (NSTRIP * GY)       // 2048 edge blocks == 256 CU * 8 blocks/CU
#define NKPB 16                // kp handled by wave 0 of blocks 0..15
#define KPOFF NB

#define MASK_W 1.0f
#define KPT_W 0.5f

struct Raw2 { float x, y, h; };               // raw row: 2 pixels + edge-lane halo
struct Prep2 { float dx0, dx1, s0, s1; };

__device__ __forceinline__ float fast_sqrt(float v) {
    return __builtin_amdgcn_sqrtf(v);
}

// Issue loads only; cross-lane shuffles deferred to consume time.
__device__ __forceinline__ Raw2 load2(const float* __restrict__ p, bool rvalid,
                                      bool hval, bool isL) {
    Raw2 r;
    if (rvalid) { float2 v = *(const float2*)p; r.x = v.x; r.y = v.y; }
    else        { r.x = 0.f; r.y = 0.f; }
    r.h = 0.f;
    if (rvalid & hval) r.h = isL ? p[-1] : p[2];
    return r;
}

__device__ __forceinline__ Prep2 fin2(const Raw2& r, bool isL, bool isR) {
    float lf = __shfl_up(r.y, 1);    // img[c-1] from prev lane
    float rf = __shfl_down(r.x, 1);  // img[c+2] from next lane
    lf = isL ? r.h : lf;
    rf = isR ? r.h : rf;
    Prep2 o;
    o.dx0 = r.y - lf;
    o.dx1 = rf  - r.x;
    o.s0 = __fmaf_rn(2.f, r.x, lf  + r.y);
    o.s1 = __fmaf_rn(2.f, r.y, r.x + rf);
    return o;
}

__device__ __forceinline__ float edge1(float dxA, float dxB, float dxC, float sA, float sC) {
    float ex = dxA + __fmaf_rn(2.f, dxB, dxC);
    float ey = sC - sA;
    return fast_sqrt(__fmaf_rn(ex, ex, ey * ey));
}

__global__ __launch_bounds__(BX, 8) void fused_kernel(const float* __restrict__ pred,
                                                      const float* __restrict__ targ,
                                                      const float* __restrict__ kp,
                                                      float* __restrict__ ws) {
    int bid = blockIdx.x;
    int t   = threadIdx.x;
    int lane = t & 63;

    // ---------------- keypoint preamble: wave 0 of blocks 0..15 ----------------
    if (bid < NKPB && t < 64) {
        int k = bid * 64 + t;
        float gxx = kp[2 * k];
        float gyy = kp[2 * k + 1];
        float x = (gxx + 1.f) * (W * 0.5f) - 0.5f;
        float y = (gyy + 1.f) * (H * 0.5f) - 0.5f;
        float fx0 = floorf(x), fy0 = floorf(y);
        int x0 = (int)fx0, y0 = (int)fy0;
        int x1 = x0 + 1, y1 = y0 + 1;
        float wx1 = x - fx0, wx0 = 1.f - wx1;
        float wy1 = y - fy0, wy0 = 1.f - wy1;

        // rolling 3x6 seg window; accumulate 2x2 box-summed distance map
        float s0r[6], s1r[6], s2r[6];
        #pragma unroll
        for (int j = 0; j < 6; ++j) {
            int cc = x0 - 2 + j;
            bool okc = (cc >= 0) & (cc < W);
            int r_ = y0 - 2;
            bool ok0 = okc & (r_ >= 0) & (r_ < H);
            s0r[j] = ok0 ? pred[(size_t)r_ * W + cc] : 0.f;
            int r1_ = y0 - 1;
            bool ok1 = okc & (r1_ >= 0) & (r1_ < H);
            s1r[j] = ok1 ? pred[(size_t)r1_ * W + cc] : 0.f;
        }
        float dm00 = 0.f, dm01 = 0.f, dm10 = 0.f, dm11 = 0.f;
        #pragma unroll
        for (int i = 0; i < 4; ++i) {
            int r2_ = y0 + i;
            #pragma unroll
            for (int j = 0; j < 6; ++j) {
                int cc = x0 - 2 + j;
                bool ok = (cc >= 0) & (cc < W) & (r2_ >= 0) & (r2_ < H);
                s2r[j] = ok ? pred[(size_t)r2_ * W + cc] : 0.f;
            }
            int rr = y0 - 1 + i;
            bool rok = (rr >= 0) & (rr < H);
            float e[4];
            #pragma unroll
            for (int j = 0; j < 4; ++j) {
                int cc = x0 - 1 + j;
                bool ok = rok & (cc >= 0) & (cc < W);
                float ex = (s0r[j + 2] - s0r[j])
                         + 2.f * (s1r[j + 2] - s1r[j])
                         + (s2r[j + 2] - s2r[j]);
                float ey = (s2r[j] + 2.f * s2r[j + 1] + s2r[j + 2])
                         - (s0r[j] + 2.f * s0r[j + 1] + s0r[j + 2]);
                e[j] = ok ? fast_sqrt(__fmaf_rn(ex, ex, ey * ey)) : 0.f;
            }
            float c0s = e[0] + e[1] + e[2];
            float c1s = e[1] + e[2] + e[3];
            if (i <= 2) { dm00 += c0s; dm01 += c1s; }
            if (i >= 1) { dm10 += c0s; dm11 += c1s; }
            #pragma unroll
            for (int j = 0; j < 6; ++j) { s0r[j] = s1r[j]; s1r[j] = s2r[j]; }
        }

        bool vx0 = (x0 >= 0) & (x0 < W), vx1 = (x1 >= 0) & (x1 < W);
        bool vy0 = (y0 >= 0) & (y0 < H), vy1 = (y1 >= 0) & (y1 < H);
        float v00 = (vx0 & vy0) ? dm00 : 0.f;
        float v01 = (vx1 & vy0) ? dm01 : 0.f;
        float v10 = (vx0 & vy1) ? dm10 : 0.f;
        float v11 = (vx1 & vy1) ? dm11 : 0.f;
        float kd = wx0 * wy0 * v00 + wx1 * wy0 * v01
                 + wx0 * wy1 * v10 + wx1 * wy1 * v11;
        #pragma unroll
        for (int m = 32; m; m >>= 1) kd += __shfl_xor(kd, m);
        if (t == 0) ws[KPOFF + bid] = kd;
    }

    // ---------------- edge-loss tile (all blocks) ----------------
    int sx = bid & (NSTRIP - 1);
    int gy = bid >> 3;                 // log2(NSTRIP)=3
    int c  = (sx << 9) + (t << 1);
    int r0 = gy * TR;
    bool isL = (lane == 0), isR = (lane == 63);
    bool hval = (isL & (c > 0)) | (isR & (c + 2 < W));

    const float* pr = pred + (ptrdiff_t)(r0 - 1) * W + c;
    const float* tr = targ + (ptrdiff_t)(r0 - 1) * W + c;

    Raw2 rpA = load2(pr, r0 > 0, hval, isL); pr += W;
    Raw2 rtA = load2(tr, r0 > 0, hval, isL); tr += W;
    Raw2 rpB = load2(pr, true,   hval, isL); pr += W;
    Raw2 rtB = load2(tr, true,   hval, isL); tr += W;
    Raw2 rpn = load2(pr, true,   hval, isL); pr += W;   // row r0+1
    Raw2 rtn = load2(tr, true,   hval, isL); tr += W;

    Prep2 pA = fin2(rpA, isL, isR);
    Prep2 tA = fin2(rtA, isL, isR);
    Prep2 pB = fin2(rpB, isL, isR);
    Prep2 tB = fin2(rtB, isL, isR);

    float acc = 0.f;
    #pragma unroll
    for (int i = 0; i < TR; ++i) {
        Raw2 rpc = rpn, rtc = rtn;
        if (i < TR - 1) {                     // issue row r0+i+2
            bool nv = (r0 + i + 2) < H;
            rpn = load2(pr, nv, hval, isL); pr += W;
            rtn = load2(tr, nv, hval, isL); tr += W;
        }
        Prep2 pC = fin2(rpc, isL, isR);
        Prep2 tC = fin2(rtc, isL, isR);

        float pe, te, d;
        pe = edge1(pA.dx0, pB.dx0, pC.dx0, pA.s0, pC.s0);
        te = edge1(tA.dx0, tB.dx0, tC.dx0, tA.s0, tC.s0);
        d = pe - te; acc = __fmaf_rn(d, d, acc);
        pe = edge1(pA.dx1, pB.dx1, pC.dx1, pA.s1, pC.s1);
        te = edge1(tA.dx1, tB.dx1, tC.dx1, tA.s1, tC.s1);
        d = pe - te; acc = __fmaf_rn(d, d, acc);

        pA = pB; pB = pC;
        tA = tB; tB = tC;
    }

    // wave reduce (width 64)
    #pragma unroll
    for (int m = 32; m; m >>= 1) acc += __shfl_xor(acc, m);

    __shared__ float wsum[BX / 64];
    if ((t & 63) == 0) wsum[t >> 6] = acc;
    __syncthreads();
    if (t == 0) {
        float s = 0.f;
        #pragma unroll
        for (int i = 0; i < BX / 64; ++i) s += wsum[i];
        ws[bid] = s;
    }
}

__global__ __launch_bounds__(256) void final_kernel(const float* __restrict__ ws,
                                                    float* __restrict__ out) {
    int t = threadIdx.x;
    float es = 0.f;
    #pragma unroll
    for (int i = 0; i < NB / 256; ++i) es += ws[t + i * 256];
    float ks = (t < NKPB) ? ws[KPOFF + t] : 0.f;

    #pragma unroll
    for (int m = 32; m; m >>= 1) {
        es += __shfl_xor(es, m);
        ks += __shfl_xor(ks, m);
    }
    __shared__ float res[4], rks[4];
    int wid = t >> 6;
    if ((t & 63) == 0) { res[wid] = es; rks[wid] = ks; }
    __syncthreads();
    if (t == 0) {
        float e2 = res[0] + res[1] + res[2] + res[3];
        float k2 = rks[0] + rks[1] + rks[2] + rks[3];
        float edge_loss = e2 * (1.f / ((float)H * (float)W));
        float constraint_loss = k2 * (1.f / 1024.f);
        out[0] = MASK_W * edge_loss + KPT_W * constraint_loss;
    }
}

extern "C" void kernel_launch(void* const* d_in, const int* in_sizes, int n_in,
                              void* d_out, int out_size, void* d_ws, size_t ws_size,
                              hipStream_t stream) {
    const float* kp   = (const float*)d_in[0];
    const float* pred = (const float*)d_in[2];
    const float* targ = (const float*)d_in[3];
    float* out = (float*)d_out;
    float* ws  = (float*)d_ws;

    fused_kernel<<<NB, BX, 0, stream>>>(pred, targ, kp, ws);
    final_kernel<<<1, 256, 0, stream>>>(ws, out);
}

// Round 13
// 162.110 us; speedup vs baseline: 1.9088x; 1.9088x over previous
//
#include <hip/hip_runtime.h>

#define H 4096
#define W 4096
#define TR 16                  // rows per block
#define BX 256                 // threads per block (4 waves)
#define SW 512                 // strip width = BX * 2 cols
#define NSTRIP (W / SW)        // 8
#define GY (H / TR)            // 256
#define NB (NSTRIP * GY)       // 2048 edge blocks == 256 CU * 8 blocks/CU
#define NKPB 16                // kp handled by wave 0 of blocks 0..15
#define KPOFF NB

#define MASK_W 1.0f
#define KPT_W 0.5f

struct Raw2 { float x, y, h; };               // raw row: 2 pixels + edge-lane halo
struct Prep2 { float dx0, dx1, s0, s1; };

__device__ __forceinline__ float fast_sqrt(float v) {
    return __builtin_amdgcn_sqrtf(v);
}

// Issue loads only; cross-lane shuffles deferred to consume time.
__device__ __forceinline__ Raw2 load2(const float* __restrict__ p, bool rvalid,
                                      bool hval, bool isL) {
    Raw2 r;
    if (rvalid) { float2 v = *(const float2*)p; r.x = v.x; r.y = v.y; }
    else        { r.x = 0.f; r.y = 0.f; }
    r.h = 0.f;
    if (rvalid & hval) r.h = isL ? p[-1] : p[2];
    return r;
}

__device__ __forceinline__ Prep2 fin2(const Raw2& r, bool isL, bool isR) {
    float lf = __shfl_up(r.y, 1);    // img[c-1] from prev lane
    float rf = __shfl_down(r.x, 1);  // img[c+2] from next lane
    lf = isL ? r.h : lf;
    rf = isR ? r.h : rf;
    Prep2 o;
    o.dx0 = r.y - lf;
    o.dx1 = rf  - r.x;
    o.s0 = __fmaf_rn(2.f, r.x, lf  + r.y);
    o.s1 = __fmaf_rn(2.f, r.y, r.x + rf);
    return o;
}

__device__ __forceinline__ float edge1(float dxA, float dxB, float dxC, float sA, float sC) {
    float ex = dxA + __fmaf_rn(2.f, dxB, dxC);
    float ey = sC - sA;
    return fast_sqrt(__fmaf_rn(ex, ex, ey * ey));
}

__global__ __launch_bounds__(BX) void fused_kernel(const float* __restrict__ pred,
                                                   const float* __restrict__ targ,
                                                   const float* __restrict__ kp,
                                                   float* __restrict__ ws) {
    int bid = blockIdx.x;
    int t   = threadIdx.x;
    int lane = t & 63;

    // ---------------- keypoint preamble: wave 0 of blocks 0..15 ----------------
    if (bid < NKPB && t < 64) {
        int k = bid * 64 + t;
        float gxx = kp[2 * k];
        float gyy = kp[2 * k + 1];
        float x = (gxx + 1.f) * (W * 0.5f) - 0.5f;
        float y = (gyy + 1.f) * (H * 0.5f) - 0.5f;
        float fx0 = floorf(x), fy0 = floorf(y);
        int x0 = (int)fx0, y0 = (int)fy0;
        int x1 = x0 + 1, y1 = y0 + 1;
        float wx1 = x - fx0, wx0 = 1.f - wx1;
        float wy1 = y - fy0, wy0 = 1.f - wy1;

        // rolling 3x6 seg window; accumulate 2x2 box-summed distance map
        float s0r[6], s1r[6], s2r[6];
        #pragma unroll
        for (int j = 0; j < 6; ++j) {
            int cc = x0 - 2 + j;
            bool okc = (cc >= 0) & (cc < W);
            int r_ = y0 - 2;
            bool ok0 = okc & (r_ >= 0) & (r_ < H);
            s0r[j] = ok0 ? pred[(size_t)r_ * W + cc] : 0.f;
            int r1_ = y0 - 1;
            bool ok1 = okc & (r1_ >= 0) & (r1_ < H);
            s1r[j] = ok1 ? pred[(size_t)r1_ * W + cc] : 0.f;
        }
        float dm00 = 0.f, dm01 = 0.f, dm10 = 0.f, dm11 = 0.f;
        #pragma unroll
        for (int i = 0; i < 4; ++i) {
            int r2_ = y0 + i;
            #pragma unroll
            for (int j = 0; j < 6; ++j) {
                int cc = x0 - 2 + j;
                bool ok = (cc >= 0) & (cc < W) & (r2_ >= 0) & (r2_ < H);
                s2r[j] = ok ? pred[(size_t)r2_ * W + cc] : 0.f;
            }
            int rr = y0 - 1 + i;
            bool rok = (rr >= 0) & (rr < H);
            float e[4];
            #pragma unroll
            for (int j = 0; j < 4; ++j) {
                int cc = x0 - 1 + j;
                bool ok = rok & (cc >= 0) & (cc < W);
                float ex = (s0r[j + 2] - s0r[j])
                         + 2.f * (s1r[j + 2] - s1r[j])
                         + (s2r[j + 2] - s2r[j]);
                float ey = (s2r[j] + 2.f * s2r[j + 1] + s2r[j + 2])
                         - (s0r[j] + 2.f * s0r[j + 1] + s0r[j + 2]);
                e[j] = ok ? fast_sqrt(__fmaf_rn(ex, ex, ey * ey)) : 0.f;
            }
            float c0s = e[0] + e[1] + e[2];
            float c1s = e[1] + e[2] + e[3];
            if (i <= 2) { dm00 += c0s; dm01 += c1s; }
            if (i >= 1) { dm10 += c0s; dm11 += c1s; }
            #pragma unroll
            for (int j = 0; j < 6; ++j) { s0r[j] = s1r[j]; s1r[j] = s2r[j]; }
        }

        bool vx0 = (x0 >= 0) & (x0 < W), vx1 = (x1 >= 0) & (x1 < W);
        bool vy0 = (y0 >= 0) & (y0 < H), vy1 = (y1 >= 0) & (y1 < H);
        float v00 = (vx0 & vy0) ? dm00 : 0.f;
        float v01 = (vx1 & vy0) ? dm01 : 0.f;
        float v10 = (vx0 & vy1) ? dm10 : 0.f;
        float v11 = (vx1 & vy1) ? dm11 : 0.f;
        float kd = wx0 * wy0 * v00 + wx1 * wy0 * v01
                 + wx0 * wy1 * v10 + wx1 * wy1 * v11;
        #pragma unroll
        for (int m = 32; m; m >>= 1) kd += __shfl_xor(kd, m);
        if (t == 0) ws[KPOFF + bid] = kd;
    }

    // ---------------- edge-loss tile (all blocks) ----------------
    int sx = bid & (NSTRIP - 1);
    int gy = bid >> 3;                 // log2(NSTRIP)=3
    int c  = (sx << 9) + (t << 1);
    int r0 = gy * TR;
    bool isL = (lane == 0), isR = (lane == 63);
    bool hval = (isL & (c > 0)) | (isR & (c + 2 < W));

    const float* pr = pred + (ptrdiff_t)(r0 - 1) * W + c;
    const float* tr = targ + (ptrdiff_t)(r0 - 1) * W + c;

    Raw2 rpA = load2(pr, r0 > 0, hval, isL); pr += W;
    Raw2 rtA = load2(tr, r0 > 0, hval, isL); tr += W;
    Raw2 rpB = load2(pr, true,   hval, isL); pr += W;
    Raw2 rtB = load2(tr, true,   hval, isL); tr += W;
    Raw2 rpn = load2(pr, true,   hval, isL); pr += W;   // row r0+1
    Raw2 rtn = load2(tr, true,   hval, isL); tr += W;

    Prep2 pA = fin2(rpA, isL, isR);
    Prep2 tA = fin2(rtA, isL, isR);
    Prep2 pB = fin2(rpB, isL, isR);
    Prep2 tB = fin2(rtB, isL, isR);

    float acc = 0.f;
    #pragma unroll
    for (int i = 0; i < TR; ++i) {
        Raw2 rpc = rpn, rtc = rtn;
        if (i < TR - 1) {                     // issue row r0+i+2
            bool nv = (r0 + i + 2) < H;
            rpn = load2(pr, nv, hval, isL); pr += W;
            rtn = load2(tr, nv, hval, isL); tr += W;
        }
        Prep2 pC = fin2(rpc, isL, isR);
        Prep2 tC = fin2(rtc, isL, isR);

        float pe, te, d;
        pe = edge1(pA.dx0, pB.dx0, pC.dx0, pA.s0, pC.s0);
        te = edge1(tA.dx0, tB.dx0, tC.dx0, tA.s0, tC.s0);
        d = pe - te; acc = __fmaf_rn(d, d, acc);
        pe = edge1(pA.dx1, pB.dx1, pC.dx1, pA.s1, pC.s1);
        te = edge1(tA.dx1, tB.dx1, tC.dx1, tA.s1, tC.s1);
        d = pe - te; acc = __fmaf_rn(d, d, acc);

        pA = pB; pB = pC;
        tA = tB; tB = tC;
    }

    // wave reduce (width 64)
    #pragma unroll
    for (int m = 32; m; m >>= 1) acc += __shfl_xor(acc, m);

    __shared__ float wsum[BX / 64];
    if ((t & 63) == 0) wsum[t >> 6] = acc;
    __syncthreads();
    if (t == 0) {
        float s = 0.f;
        #pragma unroll
        for (int i = 0; i < BX / 64; ++i) s += wsum[i];
        ws[bid] = s;
    }
}

__global__ __launch_bounds__(256) void final_kernel(const float* __restrict__ ws,
                                                    float* __restrict__ out) {
    int t = threadIdx.x;
    float es = 0.f;
    #pragma unroll
    for (int i = 0; i < NB / 256; ++i) es += ws[t + i * 256];
    float ks = (t < NKPB) ? ws[KPOFF + t] : 0.f;

    #pragma unroll
    for (int m = 32; m; m >>= 1) {
        es += __shfl_xor(es, m);
        ks += __shfl_xor(ks, m);
    }
    __shared__ float res[4], rks[4];
    int wid = t >> 6;
    if ((t & 63) == 0) { res[wid] = es; rks[wid] = ks; }
    __syncthreads();
    if (t == 0) {
        float e2 = res[0] + res[1] + res[2] + res[3];
        float k2 = rks[0] + rks[1] + rks[2] + rks[3];
        float edge_loss = e2 * (1.f / ((float)H * (float)W));
        float constraint_loss = k2 * (1.f / 1024.f);
        out[0] = MASK_W * edge_loss + KPT_W * constraint_loss;
    }
}

extern "C" void kernel_launch(void* const* d_in, const int* in_sizes, int n_in,
                              void* d_out, int out_size, void* d_ws, size_t ws_size,
                              hipStream_t stream) {
    const float* kp   = (const float*)d_in[0];
    const float* pred = (const float*)d_in[2];
    const float* targ = (const float*)d_in[3];
    float* out = (float*)d_out;
    float* ws  = (float*)d_ws;

    fused_kernel<<<NB, BX, 0, stream>>>(pred, targ, kp, ws);
    final_kernel<<<1, 256, 0, stream>>>(ws, out);
}

// Round 14
// 160.281 us; speedup vs baseline: 1.9306x; 1.0114x over previous
//
#include <hip/hip_runtime.h>

#define H 4096
#define W 4096
#define TR 16                  // rows per edge block
#define BX 256                 // threads per block (4 waves)
#define SW 512                 // strip width = BX * 2 cols
#define NSTRIP (W / SW)        // 8
#define GY (H / TR)            // 256
#define NB (NSTRIP * GY)       // 2048 edge blocks == 256 CU * 8 blocks/CU
#define NKPB 16                // exclusive keypoint blocks (64 kp each)
#define KPOFF NB

#define MASK_W 1.0f
#define KPT_W 0.5f

struct Raw2 { float x, y, h; };               // raw row: 2 pixels + edge-lane halo
struct Prep2 { float dx0, dx1, s0, s1; };

__device__ __forceinline__ float fast_sqrt(float v) {
    return __builtin_amdgcn_sqrtf(v);
}

// Issue loads only; cross-lane shuffles deferred to consume time.
__device__ __forceinline__ Raw2 load2(const float* __restrict__ p, bool rvalid,
                                      bool hval, bool isL) {
    Raw2 r;
    if (rvalid) { float2 v = *(const float2*)p; r.x = v.x; r.y = v.y; }
    else        { r.x = 0.f; r.y = 0.f; }
    r.h = 0.f;
    if (rvalid & hval) r.h = isL ? p[-1] : p[2];
    return r;
}

__device__ __forceinline__ Prep2 fin2(const Raw2& r, bool isL, bool isR) {
    float lf = __shfl_up(r.y, 1);    // img[c-1] from prev lane
    float rf = __shfl_down(r.x, 1);  // img[c+2] from next lane
    lf = isL ? r.h : lf;
    rf = isR ? r.h : rf;
    Prep2 o;
    o.dx0 = r.y - lf;
    o.dx1 = rf  - r.x;
    o.s0 = __fmaf_rn(2.f, r.x, lf  + r.y);
    o.s1 = __fmaf_rn(2.f, r.y, r.x + rf);
    return o;
}

__device__ __forceinline__ float edge1(float dxA, float dxB, float dxC, float sA, float sC) {
    float ex = dxA + __fmaf_rn(2.f, dxB, dxC);
    float ey = sC - sA;
    return fast_sqrt(__fmaf_rn(ex, ex, ey * ey));
}

__global__ __launch_bounds__(BX) void fused_kernel(const float* __restrict__ pred,
                                                   const float* __restrict__ targ,
                                                   const float* __restrict__ kp,
                                                   float* __restrict__ ws) {
    int bid = blockIdx.x;
    int t   = threadIdx.x;
    int lane = t & 63;

    if (bid < NKPB) {
        // ============ exclusive keypoint block (no merge with edge path) ============
        if (t >= 64) return;
        int k = bid * 64 + t;
        float gxx = kp[2 * k];
        float gyy = kp[2 * k + 1];
        float x = (gxx + 1.f) * (W * 0.5f) - 0.5f;
        float y = (gyy + 1.f) * (H * 0.5f) - 0.5f;
        float fx0 = floorf(x), fy0 = floorf(y);
        int x0 = (int)fx0, y0 = (int)fy0;
        int x1 = x0 + 1, y1 = y0 + 1;
        float wx1 = x - fx0, wx0 = 1.f - wx1;
        float wy1 = y - fy0, wy0 = 1.f - wy1;

        // rolling 3x6 seg window; accumulate 2x2 box-summed distance map
        float s0r[6], s1r[6], s2r[6];
        #pragma unroll
        for (int j = 0; j < 6; ++j) {
            int cc = x0 - 2 + j;
            bool okc = (cc >= 0) & (cc < W);
            int r_ = y0 - 2;
            bool ok0 = okc & (r_ >= 0) & (r_ < H);
            s0r[j] = ok0 ? pred[(size_t)r_ * W + cc] : 0.f;
            int r1_ = y0 - 1;
            bool ok1 = okc & (r1_ >= 0) & (r1_ < H);
            s1r[j] = ok1 ? pred[(size_t)r1_ * W + cc] : 0.f;
        }
        float dm00 = 0.f, dm01 = 0.f, dm10 = 0.f, dm11 = 0.f;
        #pragma unroll
        for (int i = 0; i < 4; ++i) {
            int r2_ = y0 + i;
            #pragma unroll
            for (int j = 0; j < 6; ++j) {
                int cc = x0 - 2 + j;
                bool ok = (cc >= 0) & (cc < W) & (r2_ >= 0) & (r2_ < H);
                s2r[j] = ok ? pred[(size_t)r2_ * W + cc] : 0.f;
            }
            int rr = y0 - 1 + i;
            bool rok = (rr >= 0) & (rr < H);
            float e[4];
            #pragma unroll
            for (int j = 0; j < 4; ++j) {
                int cc = x0 - 1 + j;
                bool ok = rok & (cc >= 0) & (cc < W);
                float ex = (s0r[j + 2] - s0r[j])
                         + 2.f * (s1r[j + 2] - s1r[j])
                         + (s2r[j + 2] - s2r[j]);
                float ey = (s2r[j] + 2.f * s2r[j + 1] + s2r[j + 2])
                         - (s0r[j] + 2.f * s0r[j + 1] + s0r[j + 2]);
                e[j] = ok ? fast_sqrt(__fmaf_rn(ex, ex, ey * ey)) : 0.f;
            }
            float c0s = e[0] + e[1] + e[2];
            float c1s = e[1] + e[2] + e[3];
            if (i <= 2) { dm00 += c0s; dm01 += c1s; }
            if (i >= 1) { dm10 += c0s; dm11 += c1s; }
            #pragma unroll
            for (int j = 0; j < 6; ++j) { s0r[j] = s1r[j]; s1r[j] = s2r[j]; }
        }

        bool vx0 = (x0 >= 0) & (x0 < W), vx1 = (x1 >= 0) & (x1 < W);
        bool vy0 = (y0 >= 0) & (y0 < H), vy1 = (y1 >= 0) & (y1 < H);
        float v00 = (vx0 & vy0) ? dm00 : 0.f;
        float v01 = (vx1 & vy0) ? dm01 : 0.f;
        float v10 = (vx0 & vy1) ? dm10 : 0.f;
        float v11 = (vx1 & vy1) ? dm11 : 0.f;
        float kd = wx0 * wy0 * v00 + wx1 * wy0 * v01
                 + wx0 * wy1 * v10 + wx1 * wy1 * v11;
        #pragma unroll
        for (int m = 32; m; m >>= 1) kd += __shfl_xor(kd, m);
        if (t == 0) ws[KPOFF + bid] = kd;
        return;
    }

    // ---------------- edge-loss tile ----------------
    int ebid = bid - NKPB;
    int sx = ebid & (NSTRIP - 1);
    int gy = ebid >> 3;                // log2(NSTRIP)=3
    int c  = (sx << 9) + (t << 1);
    int r0 = gy * TR;
    bool isL = (lane == 0), isR = (lane == 63);
    bool hval = (isL & (c > 0)) | (isR & (c + 2 < W));

    const float* pr = pred + (ptrdiff_t)(r0 - 1) * W + c;
    const float* tr = targ + (ptrdiff_t)(r0 - 1) * W + c;

    Raw2 rpA = load2(pr, r0 > 0, hval, isL); pr += W;
    Raw2 rtA = load2(tr, r0 > 0, hval, isL); tr += W;
    Raw2 rpB = load2(pr, true,   hval, isL); pr += W;
    Raw2 rtB = load2(tr, true,   hval, isL); tr += W;
    Raw2 rpn = load2(pr, true,   hval, isL); pr += W;   // row r0+1
    Raw2 rtn = load2(tr, true,   hval, isL); tr += W;

    Prep2 pA = fin2(rpA, isL, isR);
    Prep2 tA = fin2(rtA, isL, isR);
    Prep2 pB = fin2(rpB, isL, isR);
    Prep2 tB = fin2(rtB, isL, isR);

    float acc = 0.f;
    #pragma unroll
    for (int i = 0; i < TR; ++i) {
        Raw2 rpc = rpn, rtc = rtn;
        if (i < TR - 1) {                     // issue row r0+i+2
            bool nv = (r0 + i + 2) < H;
            rpn = load2(pr, nv, hval, isL); pr += W;
            rtn = load2(tr, nv, hval, isL); tr += W;
        }
        Prep2 pC = fin2(rpc, isL, isR);
        Prep2 tC = fin2(rtc, isL, isR);

        float pe, te, d;
        pe = edge1(pA.dx0, pB.dx0, pC.dx0, pA.s0, pC.s0);
        te = edge1(tA.dx0, tB.dx0, tC.dx0, tA.s0, tC.s0);
        d = pe - te; acc = __fmaf_rn(d, d, acc);
        pe = edge1(pA.dx1, pB.dx1, pC.dx1, pA.s1, pC.s1);
        te = edge1(tA.dx1, tB.dx1, tC.dx1, tA.s1, tC.s1);
        d = pe - te; acc = __fmaf_rn(d, d, acc);

        pA = pB; pB = pC;
        tA = tB; tB = tC;
    }

    // wave reduce (width 64)
    #pragma unroll
    for (int m = 32; m; m >>= 1) acc += __shfl_xor(acc, m);

    __shared__ float wsum[BX / 64];
    if ((t & 63) == 0) wsum[t >> 6] = acc;
    __syncthreads();
    if (t == 0) {
        float s = 0.f;
        #pragma unroll
        for (int i = 0; i < BX / 64; ++i) s += wsum[i];
        ws[ebid] = s;
    }
}

__global__ __launch_bounds__(256) void final_kernel(const float* __restrict__ ws,
                                                    float* __restrict__ out) {
    int t = threadIdx.x;
    float es = 0.f;
    #pragma unroll
    for (int i = 0; i < NB / 256; ++i) es += ws[t + i * 256];
    float ks = (t < NKPB) ? ws[KPOFF + t] : 0.f;

    #pragma unroll
    for (int m = 32; m; m >>= 1) {
        es += __shfl_xor(es, m);
        ks += __shfl_xor(ks, m);
    }
    __shared__ float res[4], rks[4];
    int wid = t >> 6;
    if ((t & 63) == 0) { res[wid] = es; rks[wid] = ks; }
    __syncthreads();
    if (t == 0) {
        float e2 = res[0] + res[1] + res[2] + res[3];
        float k2 = rks[0] + rks[1] + rks[2] + rks[3];
        float edge_loss = e2 * (1.f / ((float)H * (float)W));
        float constraint_loss = k2 * (1.f / 1024.f);
        out[0] = MASK_W * edge_loss + KPT_W * constraint_loss;
    }
}

extern "C" void kernel_launch(void* const* d_in, const int* in_sizes, int n_in,
                              void* d_out, int out_size, void* d_ws, size_t ws_size,
                              hipStream_t stream) {
    const float* kp   = (const float*)d_in[0];
    const float* pred = (const float*)d_in[2];
    const float* targ = (const float*)d_in[3];
    float* out = (float*)d_out;
    float* ws  = (float*)d_ws;

    fused_kernel<<<NB + NKPB, BX, 0, stream>>>(pred, targ, kp, ws);
    final_kernel<<<1, 256, 0, stream>>>(ws, out);
}